// Round 7
// baseline (211.679 us; speedup 1.0000x reference)
//
#include <hip/hip_runtime.h>

namespace {

constexpr int B_  = 2;
constexpr int N_  = 512;
constexpr int IN_ = 512;
constexpr int M_  = 300;   // MEM
constexpr int H_  = 64;    // HID
constexpr float SLOPE_ = 0.01f;

// ---- workspace layout (float offsets). No memsets, no atomics: every buffer
// is fully written by plain stores before it is read. ----
constexpr long OFF_W0AI = 0;                          // 512 x 64
constexpr long OFF_W0AJ = OFF_W0AI + 512L * 64;
constexpr long OFF_W1AI = OFF_W0AJ + 512L * 64;       // 300 x 64
constexpr long OFF_W1AJ = OFF_W1AI + 300L * 64;
constexpr long OFF_BSI0 = OFF_W1AJ + 300L * 64;       // 4 x 64 bias combos
constexpr long OFF_BSJ0 = OFF_BSI0 + 64;
constexpr long OFF_BSI1 = OFF_BSJ0 + 64;
constexpr long OFF_BSJ1 = OFF_BSI1 + 64;
constexpr long OFF_H0   = OFF_BSJ1 + 64;              // 1024 x 300
constexpr long OFF_SI0  = OFF_H0   + 1024L * 300;     // 1024 x 64
constexpr long OFF_SJ0  = OFF_SI0  + 1024L * 64;
constexpr long OFF_F1   = OFF_SJ0  + 1024L * 64;      // 1024 x 300
constexpr long OFF_H1   = OFF_F1   + 1024L * 300;
constexpr long OFF_SI1  = OFF_H1   + 1024L * 300;
constexpr long OFF_SJ1  = OFF_SI1  + 1024L * 64;
constexpr long OFF_ZP0  = OFF_SJ1  + 1024L * 64;      // 2 x 256 partial sums
constexpr long OFF_ZP1  = OFF_ZP0  + 512;
constexpr long OFF_P0   = OFF_ZP1  + 512;             // 2 x 512 x 512
constexpr long OFF_P1   = OFF_P0   + 2L * 512 * 512;  // total ~9.4 MB

// ---------------------------------------------------------------------------
// Multi-job fp32 GEMM: blockIdx.x -> (job, tile) via prefix offsets.
// Tile 32x32, ONE wave (64 threads), 4x4 micro-tile, TK=32, register-
// prefetched staging, plain stores. 2 B LDS / FMA (vs 3 in 2x4 config);
// single-wave block => __syncthreads is just a waitcnt (no barrier drain).
//   C = (Zp ? 1/sum(Zp[0..255]) : 1) * A@W + bias
// All tails guarded (zero-fill into LDS; predicated stores; rows clamp).
// ---------------------------------------------------------------------------
struct Jobs {
    const float* A[8]; const float* W[8]; const float* bias[8]; const float* Zp[8];
    float* C[8];
    int K[8]; int lda[8]; int Cc[8]; int R[8];
    int off[8]; int njobs;
};

__global__ __launch_bounds__(64)
void gemm_multi(Jobs jb)
{
    __shared__ __align__(16) float As[32][36];  // [k][m]; 36f=144B rows: 16B-aligned
    __shared__ __align__(16) float Ws[32][36];  // [k][n]

    const int bid = blockIdx.x;
    int j = jb.njobs - 1;
    while (j > 0 && bid < jb.off[j]) --j;
    const int local = bid - jb.off[j];

    const float* __restrict__ A = jb.A[j];
    const float* __restrict__ W = jb.W[j];
    const float* bias = jb.bias[j];
    const float* Zp   = jb.Zp[j];
    float* __restrict__ C = jb.C[j];
    const int K = jb.K[j], lda = jb.lda[j], Cc = jb.Cc[j], R = jb.R[j];

    const int tx   = (Cc + 31) >> 5;
    const int row0 = (local / tx) * 32;
    const int col0 = (local % tx) * 32;

    const int t  = threadIdx.x;
    const int sr = t >> 1;               // staging row / k-row (0..31)
    const int sg = (t & 1) * 16;         // staging k/col sub-offset (0 or 16)
    const int arow = min(row0 + sr, R - 1);
    const int tm0 = (t >> 3) * 4;        // 0..28
    const int tn0 = (t & 7) * 4;         // 0..28

    // A slab [k0, k0+32): thread loads A[arow][k0+sg .. +15] (4 x float4)
    auto loadA = [&](int k0, float4 av[4]) {
        #pragma unroll
        for (int u = 0; u < 4; ++u) {
            const int k = k0 + sg + 4 * u;
            if (k + 3 < K) {
                av[u] = *(const float4*)(A + (long)arow * lda + k);
            } else {
                float tv[4];
                #pragma unroll
                for (int v = 0; v < 4; ++v)
                    tv[v] = (k + v < K) ? A[(long)arow * lda + k + v] : 0.0f;
                av[u] = make_float4(tv[0], tv[1], tv[2], tv[3]);
            }
        }
    };
    // W slab: thread loads W[k0+sr][col0+sg .. +15] (4 x float4)
    auto loadW = [&](int k0, float4 wv[4]) {
        const int gk = k0 + sr;
        #pragma unroll
        for (int u = 0; u < 4; ++u) {
            const int c = col0 + sg + 4 * u;
            if (gk < K && c + 3 < Cc) {
                wv[u] = *(const float4*)(W + (long)gk * Cc + c);
            } else {
                float tv[4];
                #pragma unroll
                for (int v = 0; v < 4; ++v)
                    tv[v] = (gk < K && c + v < Cc) ? W[(long)gk * Cc + c + v] : 0.0f;
                wv[u] = make_float4(tv[0], tv[1], tv[2], tv[3]);
            }
        }
    };

    float acc[4][4] = {};
    float4 av[4], wv[4];
    loadA(0, av);
    loadW(0, wv);

    for (int k0 = 0; k0 < K; k0 += 32) {
        #pragma unroll
        for (int u = 0; u < 4; ++u) {       // A transposed into [k][m]
            As[sg + 4 * u + 0][sr] = av[u].x;
            As[sg + 4 * u + 1][sr] = av[u].y;
            As[sg + 4 * u + 2][sr] = av[u].z;
            As[sg + 4 * u + 3][sr] = av[u].w;
            *(float4*)&Ws[sr][sg + 4 * u] = wv[u];
        }
        __syncthreads();                    // single wave: compiles to waitcnt

        if (k0 + 32 < K) {                  // prefetch next slab behind compute
            loadA(k0 + 32, av);
            loadW(k0 + 32, wv);
        }

        #pragma unroll
        for (int k = 0; k < 32; ++k) {
            const float4 a4 = *(const float4*)&As[k][tm0];
            const float4 w4 = *(const float4*)&Ws[k][tn0];
            const float aa[4] = {a4.x, a4.y, a4.z, a4.w};
            const float ww[4] = {w4.x, w4.y, w4.z, w4.w};
            #pragma unroll
            for (int i = 0; i < 4; ++i)
                #pragma unroll
                for (int jj = 0; jj < 4; ++jj)
                    acc[i][jj] = fmaf(aa[i], ww[jj], acc[i][jj]);
        }
        __syncthreads();
    }

    float scale = 1.0f;
    if (Zp != nullptr) {                    // softmax denom from tile partials
        float s0 = 0.f, s1 = 0.f, s2 = 0.f, s3 = 0.f;
        for (int u = 0; u < 256; u += 4) {
            s0 += Zp[u]; s1 += Zp[u + 1]; s2 += Zp[u + 2]; s3 += Zp[u + 3];
        }
        scale = 1.0f / ((s0 + s1) + (s2 + s3));
    }
    const int cbase = col0 + tn0;
    float bv[4] = {0.f, 0.f, 0.f, 0.f};
    if (bias != nullptr) {
        #pragma unroll
        for (int u = 0; u < 4; ++u)
            if (cbase + u < Cc) bv[u] = bias[cbase + u];
    }
    #pragma unroll
    for (int i = 0; i < 4; ++i) {
        const int r = row0 + tm0 + i;
        if (r < R) {
            if (cbase + 3 < Cc) {
                float4 o;
                o.x = fmaf(acc[i][0], scale, bv[0]);
                o.y = fmaf(acc[i][1], scale, bv[1]);
                o.z = fmaf(acc[i][2], scale, bv[2]);
                o.w = fmaf(acc[i][3], scale, bv[3]);
                *(float4*)(C + (long)r * Cc + cbase) = o;
            } else {
                #pragma unroll
                for (int u = 0; u < 4; ++u)
                    if (cbase + u < Cc)
                        C[(long)r * Cc + cbase + u] = fmaf(acc[i][u], scale, bv[u]);
            }
        }
    }
}

// ---------------------------------------------------------------------------
// Attention numerator (32i x 32j tile per block):
//   e = leaky_relu( sum_h relu(si[i,h]+sj[j,h]) * a2w[h] + a2b )
//   p = adj * exp(e);  Zpart[b*256+tile] = sum(p)  (plain store — no atomics)
// Max-subtraction skipped: |e| = O(10), fp32 exp exact-safe; softmax is over
// the flat N*N per batch so sum(Zpart) is the exact denominator.
// ---------------------------------------------------------------------------
__global__ __launch_bounds__(256)
void attn_p_kernel(const float* __restrict__ si, const float* __restrict__ sj,
                   const float* __restrict__ adj, const float* __restrict__ a2w,
                   const float* __restrict__ a2b, float* __restrict__ p,
                   float* __restrict__ Zpart)
{
    __shared__ __align__(16) float Si[32][68];
    __shared__ __align__(16) float Sj[32][68];

    const int b  = blockIdx.z;
    const int i0 = blockIdx.y * 32;
    const int j0 = blockIdx.x * 32;
    const int t  = threadIdx.x;

    {   // stage 32x64 tiles of si and sj
        const int r  = t >> 3;
        const int hc = (t & 7) * 8;
        const float* gi = si + ((long)(b * N_ + i0 + r)) * H_ + hc;
        const float* gj = sj + ((long)(b * N_ + j0 + r)) * H_ + hc;
        *(float4*)&Si[r][hc]     = *(const float4*)(gi);
        *(float4*)&Si[r][hc + 4] = *(const float4*)(gi + 4);
        *(float4*)&Sj[r][hc]     = *(const float4*)(gj);
        *(float4*)&Sj[r][hc + 4] = *(const float4*)(gj + 4);
    }
    __syncthreads();

    const int i  = t >> 3;
    const int jl = t & 7;

    float e[4] = {0.f, 0.f, 0.f, 0.f};
    #pragma unroll
    for (int h0 = 0; h0 < H_; h0 += 4) {
        const float4 a4 = *(const float4*)&Si[i][h0];
        const float w0v = a2w[h0 + 0];
        const float w1v = a2w[h0 + 1];
        const float w2v = a2w[h0 + 2];
        const float w3v = a2w[h0 + 3];
        #pragma unroll
        for (int u = 0; u < 4; ++u) {
            const float4 b4 = *(const float4*)&Sj[jl + 8 * u][h0];
            e[u] = fmaf(fmaxf(a4.x + b4.x, 0.f), w0v, e[u]);
            e[u] = fmaf(fmaxf(a4.y + b4.y, 0.f), w1v, e[u]);
            e[u] = fmaf(fmaxf(a4.z + b4.z, 0.f), w2v, e[u]);
            e[u] = fmaf(fmaxf(a4.w + b4.w, 0.f), w3v, e[u]);
        }
    }

    const float a2bv = a2b[0];
    const long rowbase = ((long)(b * N_ + i0 + i)) * N_ + j0 + jl;
    float lsum = 0.f;
    #pragma unroll
    for (int u = 0; u < 4; ++u) {
        float ev = e[u] + a2bv;
        ev = (ev >= 0.f) ? ev : SLOPE_ * ev;
        const float m  = adj[rowbase + 8 * u];
        const float pv = m * __expf(ev);
        p[rowbase + 8 * u] = pv;
        lsum += pv;
    }

    #pragma unroll
    for (int off = 32; off > 0; off >>= 1)
        lsum += __shfl_down(lsum, off, 64);
    __shared__ float red[4];
    if ((t & 63) == 0) red[t >> 6] = lsum;
    __syncthreads();
    if (t == 0)
        Zpart[b * 256 + blockIdx.y * 16 + blockIdx.x] =
            red[0] + red[1] + red[2] + red[3];
}

} // namespace

extern "C" void kernel_launch(void* const* d_in, const int* in_sizes, int n_in,
                              void* d_out, int out_size, void* d_ws, size_t ws_size,
                              hipStream_t stream)
{
    const float* feature = (const float*)d_in[0];
    const float* adj     = (const float*)d_in[1];
    const float* w0      = (const float*)d_in[2];
    const float* b0      = (const float*)d_in[3];
    const float* w1      = (const float*)d_in[4];
    const float* b1      = (const float*)d_in[5];
    const float* a1w     = (const float*)d_in[6];   // (600, 64) row-major
    const float* a1b     = (const float*)d_in[7];
    const float* a2w     = (const float*)d_in[8];
    const float* a2b     = (const float*)d_in[9];
    float* out = (float*)d_out;
    float* ws  = (float*)d_ws;

    float* cW0Ai = ws + OFF_W0AI;
    float* cW0Aj = ws + OFF_W0AJ;
    float* cW1Ai = ws + OFF_W1AI;
    float* cW1Aj = ws + OFF_W1AJ;
    float* bsi0  = ws + OFF_BSI0;
    float* bsj0  = ws + OFF_BSJ0;
    float* bsi1  = ws + OFF_BSI1;
    float* bsj1  = ws + OFF_BSJ1;
    float* h0    = ws + OFF_H0;
    float* si0   = ws + OFF_SI0;
    float* sj0   = ws + OFF_SJ0;
    float* f1    = ws + OFF_F1;
    float* h1    = ws + OFF_H1;
    float* si1   = ws + OFF_SI1;
    float* sj1   = ws + OFF_SJ1;
    float* Zp0   = ws + OFF_ZP0;
    float* Zp1   = ws + OFF_ZP1;
    float* p0    = ws + OFF_P0;
    float* p1    = ws + OFF_P1;

    const float* Ai = a1w;                    // top half (300 x 64)
    const float* Aj = a1w + (long)M_ * H_;    // bottom half

    auto set_job = [](Jobs& jb, int j, const float* A, const float* W,
                      const float* bias, const float* Zp, float* C,
                      int K, int lda, int Cc, int R, int& tiles) {
        jb.A[j] = A; jb.W[j] = W; jb.bias[j] = bias; jb.Zp[j] = Zp; jb.C[j] = C;
        jb.K[j] = K; jb.lda[j] = lda; jb.Cc[j] = Cc; jb.R[j] = R;
        jb.off[j] = tiles;
        tiles += ((R + 31) / 32) * ((Cc + 31) / 32);
    };

    // ---- D1: fused attention-projection weights + bias combos ----
    // si = h@Ai = x@(w@Ai) + (b@Ai);  sj = x@(w@Aj) + (b@Aj + a1b)
    {
        Jobs jb; int tiles = 0;
        set_job(jb, 0, w0, Ai, nullptr, nullptr, cW0Ai, M_, M_, H_, IN_, tiles);
        set_job(jb, 1, w0, Aj, nullptr, nullptr, cW0Aj, M_, M_, H_, IN_, tiles);
        set_job(jb, 2, w1, Ai, nullptr, nullptr, cW1Ai, M_, M_, H_, M_,  tiles);
        set_job(jb, 3, w1, Aj, nullptr, nullptr, cW1Aj, M_, M_, H_, M_,  tiles);
        set_job(jb, 4, b0, Ai, nullptr, nullptr, bsi0,  M_, M_, H_, 1,   tiles);
        set_job(jb, 5, b0, Aj, a1b,     nullptr, bsj0,  M_, M_, H_, 1,   tiles);
        set_job(jb, 6, b1, Ai, nullptr, nullptr, bsi1,  M_, M_, H_, 1,   tiles);
        set_job(jb, 7, b1, Aj, a1b,     nullptr, bsj1,  M_, M_, H_, 1,   tiles);
        jb.njobs = 8;
        gemm_multi<<<dim3(tiles), dim3(64), 0, stream>>>(jb);   // 112 blocks
    }

    // ---- D2: layer-0 node projection + attention features (independent) ----
    {
        Jobs jb; int tiles = 0;
        set_job(jb, 0, feature, w0,    b0,   nullptr, h0,  IN_, IN_, M_, 1024, tiles);
        set_job(jb, 1, feature, cW0Ai, bsi0, nullptr, si0, IN_, IN_, H_, 1024, tiles);
        set_job(jb, 2, feature, cW0Aj, bsj0, nullptr, sj0, IN_, IN_, H_, 1024, tiles);
        jb.njobs = 3;
        gemm_multi<<<dim3(tiles), dim3(64), 0, stream>>>(jb);   // 448 blocks
    }

    // ---- D3: p0 + Zpart0 ----
    attn_p_kernel<<<dim3(16, 16, B_), dim3(256), 0, stream>>>(
        si0, sj0, adj, a2w, a2b, p0, Zp0);

    // ---- D4: f1 = (1/Z0[b]) * p0 @ h0 ----
    {
        Jobs jb; int tiles = 0;
        set_job(jb, 0, p0,               h0,              nullptr, Zp0,       f1,
                N_, N_, M_, N_, tiles);
        set_job(jb, 1, p0 + (long)N_*N_, h0 + (long)N_*M_, nullptr, Zp0 + 256,
                f1 + (long)N_*M_, N_, N_, M_, N_, tiles);
        jb.njobs = 2;
        gemm_multi<<<dim3(tiles), dim3(64), 0, stream>>>(jb);   // 320 blocks
    }

    // ---- D5: layer-1 projections (independent given f1) ----
    {
        Jobs jb; int tiles = 0;
        set_job(jb, 0, f1, w1,    b1,   nullptr, h1,  M_, M_, M_, 1024, tiles);
        set_job(jb, 1, f1, cW1Ai, bsi1, nullptr, si1, M_, M_, H_, 1024, tiles);
        set_job(jb, 2, f1, cW1Aj, bsj1, nullptr, sj1, M_, M_, H_, 1024, tiles);
        jb.njobs = 3;
        gemm_multi<<<dim3(tiles), dim3(64), 0, stream>>>(jb);   // 448 blocks
    }

    // ---- D6: p1 + Zpart1 ----
    attn_p_kernel<<<dim3(16, 16, B_), dim3(256), 0, stream>>>(
        si1, sj1, adj, a2w, a2b, p1, Zp1);

    // ---- D7: out = (1/Z1[b]) * p1 @ h1 ----
    {
        Jobs jb; int tiles = 0;
        set_job(jb, 0, p1,               h1,              nullptr, Zp1,       out,
                N_, N_, M_, N_, tiles);
        set_job(jb, 1, p1 + (long)N_*N_, h1 + (long)N_*M_, nullptr, Zp1 + 256,
                out + (long)N_*M_, N_, N_, M_, N_, tiles);
        jb.njobs = 2;
        gemm_multi<<<dim3(tiles), dim3(64), 0, stream>>>(jb);   // 320 blocks
    }
}

// Round 8
// 197.657 us; speedup vs baseline: 1.0709x; 1.0709x over previous
//
#include <hip/hip_runtime.h>

namespace {

constexpr int B_  = 2;
constexpr int N_  = 512;
constexpr int IN_ = 512;
constexpr int M_  = 300;   // MEM
constexpr int H_  = 64;    // HID
constexpr float SLOPE_ = 0.01f;

// ---- workspace layout (float offsets). No memsets, no atomics: every buffer
// is fully written by plain stores before it is read. ----
constexpr long OFF_W0AI = 0;                          // 512 x 64
constexpr long OFF_W0AJ = OFF_W0AI + 512L * 64;
constexpr long OFF_W1AI = OFF_W0AJ + 512L * 64;       // 300 x 64
constexpr long OFF_W1AJ = OFF_W1AI + 300L * 64;
constexpr long OFF_BSI0 = OFF_W1AJ + 300L * 64;       // 4 x 64 bias combos
constexpr long OFF_BSJ0 = OFF_BSI0 + 64;
constexpr long OFF_BSI1 = OFF_BSJ0 + 64;
constexpr long OFF_BSJ1 = OFF_BSI1 + 64;
constexpr long OFF_H0   = OFF_BSJ1 + 64;              // 1024 x 300
constexpr long OFF_SI0  = OFF_H0   + 1024L * 300;     // 1024 x 64
constexpr long OFF_SJ0  = OFF_SI0  + 1024L * 64;
constexpr long OFF_F1   = OFF_SJ0  + 1024L * 64;      // 1024 x 300
constexpr long OFF_H1   = OFF_F1   + 1024L * 300;
constexpr long OFF_SI1  = OFF_H1   + 1024L * 300;
constexpr long OFF_SJ1  = OFF_SI1  + 1024L * 64;
constexpr long OFF_ZP0  = OFF_SJ1  + 1024L * 64;      // 2 x 256 partial sums
constexpr long OFF_ZP1  = OFF_ZP0  + 512;
constexpr long OFF_P0   = OFF_ZP1  + 512;             // 2 x 512 x 512
constexpr long OFF_P1   = OFF_P0   + 2L * 512 * 512;  // total ~9.4 MB

// ---------------------------------------------------------------------------
// Multi-job fp32 GEMM: blockIdx.x -> (job, tile) via prefix offsets.
// Tile 64x64, 256 threads (4 waves), 4x4 micro-tile, TK=16, register-
// prefetched staging, plain stores (no atomics / split-K).
//   2 B LDS per FMA -> VALU-bound (~128 FMA/cyc/CU); 4 waves/block keep all
//   4 SIMDs fed and hide global-prefetch + LDS latency (R7's 1-wave mistake).
//   C = (Zp ? 1/sum(Zp[0..255]) : 1) * A@W + bias
// All tails guarded (zero-fill LDS, row clamp for R=1 jobs, predicated store).
// ---------------------------------------------------------------------------
struct Jobs {
    const float* A[8]; const float* W[8]; const float* bias[8]; const float* Zp[8];
    float* C[8];
    int K[8]; int lda[8]; int Cc[8]; int R[8];
    int off[8]; int njobs;
};

__global__ __launch_bounds__(256)
void gemm_multi(Jobs jb)
{
    __shared__ __align__(16) float As[16][68];  // [k][m]; stride 68: <=2-way (free)
    __shared__ __align__(16) float Ws[16][64];  // [k][n]

    const int bid = blockIdx.x;
    int j = jb.njobs - 1;
    while (j > 0 && bid < jb.off[j]) --j;
    const int local = bid - jb.off[j];

    const float* __restrict__ A = jb.A[j];
    const float* __restrict__ W = jb.W[j];
    const float* bias = jb.bias[j];
    const float* Zp   = jb.Zp[j];
    float* __restrict__ C = jb.C[j];
    const int K = jb.K[j], lda = jb.lda[j], Cc = jb.Cc[j], R = jb.R[j];

    const int tx   = (Cc + 63) >> 6;
    const int row0 = (local / tx) * 64;
    const int col0 = (local % tx) * 64;

    const int t    = threadIdx.x;
    const int arow = min(row0 + (t >> 2), R - 1);  // clamp: R=1 bias jobs
    const int akg  = (t & 3) * 4;                  // A k sub-offset (0,4,8,12)
    const int wk   = t >> 4;                       // W k-row 0..15
    const int wc   = (t & 15) * 4;                 // W col 0..60
    const int tm0  = (t >> 4) * 4;
    const int tn0  = (t & 15) * 4;

    auto loadA = [&](int k0) -> float4 {
        const int k = k0 + akg;
        if (k + 3 < K) return *(const float4*)(A + (long)arow * lda + k);
        float tv[4];
        #pragma unroll
        for (int v = 0; v < 4; ++v)
            tv[v] = (k + v < K) ? A[(long)arow * lda + k + v] : 0.0f;
        return make_float4(tv[0], tv[1], tv[2], tv[3]);
    };
    auto loadW = [&](int k0) -> float4 {
        const int gk = k0 + wk;
        const int c  = col0 + wc;
        if (gk < K && c + 3 < Cc) return *(const float4*)(W + (long)gk * Cc + c);
        float tv[4];
        #pragma unroll
        for (int v = 0; v < 4; ++v)
            tv[v] = (gk < K && c + v < Cc) ? W[(long)gk * Cc + c + v] : 0.0f;
        return make_float4(tv[0], tv[1], tv[2], tv[3]);
    };

    float acc[4][4] = {};
    float4 av = loadA(0);
    float4 wv = loadW(0);

    for (int k0 = 0; k0 < K; k0 += 16) {
        As[akg + 0][t >> 2] = av.x;        // transposed: As[k][m]
        As[akg + 1][t >> 2] = av.y;
        As[akg + 2][t >> 2] = av.z;
        As[akg + 3][t >> 2] = av.w;
        *(float4*)&Ws[wk][wc] = wv;
        __syncthreads();

        if (k0 + 16 < K) {                 // prefetch next slab behind compute
            av = loadA(k0 + 16);
            wv = loadW(k0 + 16);
        }

        #pragma unroll
        for (int k = 0; k < 16; ++k) {
            const float4 a4 = *(const float4*)&As[k][tm0];
            const float4 w4 = *(const float4*)&Ws[k][tn0];
            const float aa[4] = {a4.x, a4.y, a4.z, a4.w};
            const float ww[4] = {w4.x, w4.y, w4.z, w4.w};
            #pragma unroll
            for (int i = 0; i < 4; ++i)
                #pragma unroll
                for (int jj = 0; jj < 4; ++jj)
                    acc[i][jj] = fmaf(aa[i], ww[jj], acc[i][jj]);
        }
        __syncthreads();
    }

    float scale = 1.0f;
    if (Zp != nullptr) {                   // softmax denom from tile partials
        float s0 = 0.f, s1 = 0.f, s2 = 0.f, s3 = 0.f;
        for (int u = 0; u < 256; u += 4) {
            s0 += Zp[u]; s1 += Zp[u + 1]; s2 += Zp[u + 2]; s3 += Zp[u + 3];
        }
        scale = 1.0f / ((s0 + s1) + (s2 + s3));
    }
    const int cbase = col0 + tn0;
    float bv[4] = {0.f, 0.f, 0.f, 0.f};
    if (bias != nullptr) {
        #pragma unroll
        for (int u = 0; u < 4; ++u)
            if (cbase + u < Cc) bv[u] = bias[cbase + u];
    }
    #pragma unroll
    for (int i = 0; i < 4; ++i) {
        const int r = row0 + tm0 + i;
        if (r < R) {
            if (cbase + 3 < Cc) {
                float4 o;
                o.x = fmaf(acc[i][0], scale, bv[0]);
                o.y = fmaf(acc[i][1], scale, bv[1]);
                o.z = fmaf(acc[i][2], scale, bv[2]);
                o.w = fmaf(acc[i][3], scale, bv[3]);
                *(float4*)(C + (long)r * Cc + cbase) = o;
            } else {
                #pragma unroll
                for (int u = 0; u < 4; ++u)
                    if (cbase + u < Cc)
                        C[(long)r * Cc + cbase + u] = fmaf(acc[i][u], scale, bv[u]);
            }
        }
    }
}

// ---------------------------------------------------------------------------
// Attention numerator (32i x 32j tile per block):
//   e = leaky_relu( sum_h relu(si[i,h]+sj[j,h]) * a2w[h] + a2b )
//   p = adj * exp(e);  Zpart[b*256+tile] = sum(p)  (plain store — no atomics)
// Max-subtraction skipped: |e| = O(10), fp32 exp exact-safe; softmax is over
// the flat N*N per batch so sum(Zpart) is the exact denominator.
// ---------------------------------------------------------------------------
__global__ __launch_bounds__(256)
void attn_p_kernel(const float* __restrict__ si, const float* __restrict__ sj,
                   const float* __restrict__ adj, const float* __restrict__ a2w,
                   const float* __restrict__ a2b, float* __restrict__ p,
                   float* __restrict__ Zpart)
{
    __shared__ __align__(16) float Si[32][68];
    __shared__ __align__(16) float Sj[32][68];

    const int b  = blockIdx.z;
    const int i0 = blockIdx.y * 32;
    const int j0 = blockIdx.x * 32;
    const int t  = threadIdx.x;

    {   // stage 32x64 tiles of si and sj
        const int r  = t >> 3;
        const int hc = (t & 7) * 8;
        const float* gi = si + ((long)(b * N_ + i0 + r)) * H_ + hc;
        const float* gj = sj + ((long)(b * N_ + j0 + r)) * H_ + hc;
        *(float4*)&Si[r][hc]     = *(const float4*)(gi);
        *(float4*)&Si[r][hc + 4] = *(const float4*)(gi + 4);
        *(float4*)&Sj[r][hc]     = *(const float4*)(gj);
        *(float4*)&Sj[r][hc + 4] = *(const float4*)(gj + 4);
    }
    __syncthreads();

    const int i  = t >> 3;
    const int jl = t & 7;

    float e[4] = {0.f, 0.f, 0.f, 0.f};
    #pragma unroll
    for (int h0 = 0; h0 < H_; h0 += 4) {
        const float4 a4 = *(const float4*)&Si[i][h0];
        const float w0v = a2w[h0 + 0];
        const float w1v = a2w[h0 + 1];
        const float w2v = a2w[h0 + 2];
        const float w3v = a2w[h0 + 3];
        #pragma unroll
        for (int u = 0; u < 4; ++u) {
            const float4 b4 = *(const float4*)&Sj[jl + 8 * u][h0];
            e[u] = fmaf(fmaxf(a4.x + b4.x, 0.f), w0v, e[u]);
            e[u] = fmaf(fmaxf(a4.y + b4.y, 0.f), w1v, e[u]);
            e[u] = fmaf(fmaxf(a4.z + b4.z, 0.f), w2v, e[u]);
            e[u] = fmaf(fmaxf(a4.w + b4.w, 0.f), w3v, e[u]);
        }
    }

    const float a2bv = a2b[0];
    const long rowbase = ((long)(b * N_ + i0 + i)) * N_ + j0 + jl;
    float lsum = 0.f;
    #pragma unroll
    for (int u = 0; u < 4; ++u) {
        float ev = e[u] + a2bv;
        ev = (ev >= 0.f) ? ev : SLOPE_ * ev;
        const float m  = adj[rowbase + 8 * u];
        const float pv = m * __expf(ev);
        p[rowbase + 8 * u] = pv;
        lsum += pv;
    }

    #pragma unroll
    for (int off = 32; off > 0; off >>= 1)
        lsum += __shfl_down(lsum, off, 64);
    __shared__ float red[4];
    if ((t & 63) == 0) red[t >> 6] = lsum;
    __syncthreads();
    if (t == 0)
        Zpart[b * 256 + blockIdx.y * 16 + blockIdx.x] =
            red[0] + red[1] + red[2] + red[3];
}

} // namespace

extern "C" void kernel_launch(void* const* d_in, const int* in_sizes, int n_in,
                              void* d_out, int out_size, void* d_ws, size_t ws_size,
                              hipStream_t stream)
{
    const float* feature = (const float*)d_in[0];
    const float* adj     = (const float*)d_in[1];
    const float* w0      = (const float*)d_in[2];
    const float* b0      = (const float*)d_in[3];
    const float* w1      = (const float*)d_in[4];
    const float* b1      = (const float*)d_in[5];
    const float* a1w     = (const float*)d_in[6];   // (600, 64) row-major
    const float* a1b     = (const float*)d_in[7];
    const float* a2w     = (const float*)d_in[8];
    const float* a2b     = (const float*)d_in[9];
    float* out = (float*)d_out;
    float* ws  = (float*)d_ws;

    float* cW0Ai = ws + OFF_W0AI;
    float* cW0Aj = ws + OFF_W0AJ;
    float* cW1Ai = ws + OFF_W1AI;
    float* cW1Aj = ws + OFF_W1AJ;
    float* bsi0  = ws + OFF_BSI0;
    float* bsj0  = ws + OFF_BSJ0;
    float* bsi1  = ws + OFF_BSI1;
    float* bsj1  = ws + OFF_BSJ1;
    float* h0    = ws + OFF_H0;
    float* si0   = ws + OFF_SI0;
    float* sj0   = ws + OFF_SJ0;
    float* f1    = ws + OFF_F1;
    float* h1    = ws + OFF_H1;
    float* si1   = ws + OFF_SI1;
    float* sj1   = ws + OFF_SJ1;
    float* Zp0   = ws + OFF_ZP0;
    float* Zp1   = ws + OFF_ZP1;
    float* p0    = ws + OFF_P0;
    float* p1    = ws + OFF_P1;

    const float* Ai = a1w;                    // top half (300 x 64)
    const float* Aj = a1w + (long)M_ * H_;    // bottom half

    auto set_job = [](Jobs& jb, int j, const float* A, const float* W,
                      const float* bias, const float* Zp, float* C,
                      int K, int lda, int Cc, int R, int& tiles) {
        jb.A[j] = A; jb.W[j] = W; jb.bias[j] = bias; jb.Zp[j] = Zp; jb.C[j] = C;
        jb.K[j] = K; jb.lda[j] = lda; jb.Cc[j] = Cc; jb.R[j] = R;
        jb.off[j] = tiles;
        tiles += ((R + 63) / 64) * ((Cc + 63) / 64);
    };

    // ---- D1: fused attention-projection weights + bias combos ----
    // si = h@Ai = x@(w@Ai) + (b@Ai);  sj = x@(w@Aj) + (b@Aj + a1b)
    {
        Jobs jb; int tiles = 0;
        set_job(jb, 0, w0, Ai, nullptr, nullptr, cW0Ai, M_, M_, H_, IN_, tiles);
        set_job(jb, 1, w0, Aj, nullptr, nullptr, cW0Aj, M_, M_, H_, IN_, tiles);
        set_job(jb, 2, w1, Ai, nullptr, nullptr, cW1Ai, M_, M_, H_, M_,  tiles);
        set_job(jb, 3, w1, Aj, nullptr, nullptr, cW1Aj, M_, M_, H_, M_,  tiles);
        set_job(jb, 4, b0, Ai, nullptr, nullptr, bsi0,  M_, M_, H_, 1,   tiles);
        set_job(jb, 5, b0, Aj, a1b,     nullptr, bsj0,  M_, M_, H_, 1,   tiles);
        set_job(jb, 6, b1, Ai, nullptr, nullptr, bsi1,  M_, M_, H_, 1,   tiles);
        set_job(jb, 7, b1, Aj, a1b,     nullptr, bsj1,  M_, M_, H_, 1,   tiles);
        jb.njobs = 8;
        gemm_multi<<<dim3(tiles), dim3(256), 0, stream>>>(jb);  // 30 blocks
    }

    // ---- D2: layer-0 node projection + attention features (independent) ----
    {
        Jobs jb; int tiles = 0;
        set_job(jb, 0, feature, w0,    b0,   nullptr, h0,  IN_, IN_, M_, 1024, tiles);
        set_job(jb, 1, feature, cW0Ai, bsi0, nullptr, si0, IN_, IN_, H_, 1024, tiles);
        set_job(jb, 2, feature, cW0Aj, bsj0, nullptr, sj0, IN_, IN_, H_, 1024, tiles);
        jb.njobs = 3;
        gemm_multi<<<dim3(tiles), dim3(256), 0, stream>>>(jb);  // 112 blocks
    }

    // ---- D3: p0 + Zpart0 ----
    attn_p_kernel<<<dim3(16, 16, B_), dim3(256), 0, stream>>>(
        si0, sj0, adj, a2w, a2b, p0, Zp0);

    // ---- D4: f1 = (1/Z0[b]) * p0 @ h0 ----
    {
        Jobs jb; int tiles = 0;
        set_job(jb, 0, p0,               h0,              nullptr, Zp0,       f1,
                N_, N_, M_, N_, tiles);
        set_job(jb, 1, p0 + (long)N_*N_, h0 + (long)N_*M_, nullptr, Zp0 + 256,
                f1 + (long)N_*M_, N_, N_, M_, N_, tiles);
        jb.njobs = 2;
        gemm_multi<<<dim3(tiles), dim3(256), 0, stream>>>(jb);  // 80 blocks
    }

    // ---- D5: layer-1 projections (independent given f1) ----
    {
        Jobs jb; int tiles = 0;
        set_job(jb, 0, f1, w1,    b1,   nullptr, h1,  M_, M_, M_, 1024, tiles);
        set_job(jb, 1, f1, cW1Ai, bsi1, nullptr, si1, M_, M_, H_, 1024, tiles);
        set_job(jb, 2, f1, cW1Aj, bsj1, nullptr, sj1, M_, M_, H_, 1024, tiles);
        jb.njobs = 3;
        gemm_multi<<<dim3(tiles), dim3(256), 0, stream>>>(jb);  // 112 blocks
    }

    // ---- D6: p1 + Zpart1 ----
    attn_p_kernel<<<dim3(16, 16, B_), dim3(256), 0, stream>>>(
        si1, sj1, adj, a2w, a2b, p1, Zp1);

    // ---- D7: out = (1/Z1[b]) * p1 @ h1 ----
    {
        Jobs jb; int tiles = 0;
        set_job(jb, 0, p1,               h1,              nullptr, Zp1,       out,
                N_, N_, M_, N_, tiles);
        set_job(jb, 1, p1 + (long)N_*N_, h1 + (long)N_*M_, nullptr, Zp1 + 256,
                out + (long)N_*M_, N_, N_, M_, N_, tiles);
        jb.njobs = 2;
        gemm_multi<<<dim3(tiles), dim3(256), 0, stream>>>(jb);  // 80 blocks
    }
}